// Round 7
// baseline (505.228 us; speedup 1.0000x reference)
//
#include <hip/hip_runtime.h>
#include <hip/hip_cooperative_groups.h>

// InductionNetwork capsule routing, C=256, K=64, H=1024, 3 iterations.
// R6 post-mortem: 12-dispatch pipeline = serialized low-occupancy nodes
// (GEMMs ran at 1 wave/CU; enc re-read 3x). This version: ONE cooperative
// kernel, 256 blocks x 512 threads, 10 grid syncs.
//   - enc slice lives in VGPRs (er[8][4], 128 regs) for the whole kernel:
//     64 MB HBM read ONCE.
//   - W split to bf16 hi/lo (direct + transposed) in phase 0 (per-block
//     64x64 tile), L2-resident thereafter.
//   - GEMMs: split-bf16 (Ah.Bh + Ah.Bl + Al.Bh, verified R6 absmax 4.9e-4)
//     over ALL 2048 waves via split-K halves into chat0/chat1 (u0/u1).
//   - b logits live in LDS, persist across iterations; no global b.
// Fallback: R3's proven monolithic kernel if coop launch fails or ws small.

namespace cg = cooperative_groups;

using f32x4  = __attribute__((ext_vector_type(4))) float;
using f32x2  = __attribute__((ext_vector_type(2))) float;
using bf16x8 = __attribute__((ext_vector_type(8))) __bf16;
using bf16x2 = __attribute__((ext_vector_type(2))) __bf16;

struct BfPair { __bf16 hi, lo; };
__device__ inline BfPair split_bf16(float x) {
    BfPair p;
    p.hi = (__bf16)x;
    p.lo = (__bf16)(x - (float)p.hi);
    return p;
}

// Split-bf16 NT GEMM over the whole grid: 2048 waves, wave gw handles
// task=gw>>1 (mt=task>>6 in [0,16), nt=task&63 in [0,64)), K-half kh=gw&1.
// Writes 16x16 fp32 tile into C0 (kh=0) or C1 (kh=1).
// Fragment layout verified R4/R6: A[m=lane&15][k=(lane>>4)*8+j];
// C/D col=lane&15, row=(lane>>4)*4+reg.
__device__ inline void gemm_phase(
    const __bf16* __restrict__ Ah, const __bf16* __restrict__ Al,
    const __bf16* __restrict__ Bh, const __bf16* __restrict__ Bl,
    float* __restrict__ C0, float* __restrict__ C1, int gw)
{
    const int task = gw >> 1;
    const int kh   = gw & 1;
    const int mt   = task >> 6;
    const int nt   = task & 63;
    const int lane = threadIdx.x & 63;
    const int kq   = (lane >> 4) * 8 + kh * 512;
    const size_t aoff = (size_t)(mt * 16 + (lane & 15)) * 1024 + kq;
    const size_t boff = (size_t)(nt * 16 + (lane & 15)) * 1024 + kq;

    f32x4 hh = {}, hl = {}, lh = {};
    #pragma unroll 4
    for (int k0 = 0; k0 < 512; k0 += 32) {
        bf16x8 ah = *(const bf16x8*)(Ah + aoff + k0);
        bf16x8 al = *(const bf16x8*)(Al + aoff + k0);
        bf16x8 bh = *(const bf16x8*)(Bh + boff + k0);
        bf16x8 bl = *(const bf16x8*)(Bl + boff + k0);
        hh = __builtin_amdgcn_mfma_f32_16x16x32_bf16(ah, bh, hh, 0, 0, 0);
        hl = __builtin_amdgcn_mfma_f32_16x16x32_bf16(ah, bl, hl, 0, 0, 0);
        lh = __builtin_amdgcn_mfma_f32_16x16x32_bf16(al, bh, lh, 0, 0, 0);
    }
    f32x4 acc = hh + hl + lh;
    float* Cc = kh ? C1 : C0;
    const int rr = (lane >> 4) * 4, colb = lane & 15;
    #pragma unroll
    for (int r = 0; r < 4; ++r)
        Cc[(size_t)(mt * 16 + rr + r) * 1024 + nt * 16 + colb] = acc[r];
}

__global__ __launch_bounds__(512) void fused_kernel(
    const float* __restrict__ enc, const float* __restrict__ W,
    float* __restrict__ outp,
    __bf16* __restrict__ s_hi, __bf16* __restrict__ s_lo,
    __bf16* __restrict__ c_hi, __bf16* __restrict__ c_lo,
    float* __restrict__ chat0, float* __restrict__ chat1,
    float* __restrict__ u0, float* __restrict__ u1,
    __bf16* __restrict__ Wb_hi, __bf16* __restrict__ Wb_lo,
    __bf16* __restrict__ Wt_hi, __bf16* __restrict__ Wt_lo)
{
    cg::grid_group grid = cg::this_grid();
    __shared__ float spart[8][1024];   // 32 KB: per-wave partial s
    __shared__ float wtile[64][65];    // 16.6 KB: W transpose staging
    __shared__ float b_s[64];          // logits, persist across iterations
    __shared__ float d_s[64];
    __shared__ float red_s[8];

    const int t = threadIdx.x, lane = t & 63, w = t >> 6;   // 8 waves
    const int c = blockIdx.x;
    const int gw = c * 8 + w;

    // ======== P0: enc -> registers, b=0, W -> split bf16, iter-0 s ========
    // er[r][q]: wave w owns rows w*8+r; lane holds h = {lane*8..+7,
    // 512+lane*8..+7}. 128 VGPRs, live for the whole kernel.
    f32x4 er[8][4];
    {
        const float* E = enc + (size_t)c * 65536;
        #pragma unroll
        for (int r = 0; r < 8; ++r) {
            const float* ek = E + (size_t)(w * 8 + r) * 1024 + lane * 8;
            er[r][0] = *(const f32x4*)(ek);
            er[r][1] = *(const f32x4*)(ek + 4);
            er[r][2] = *(const f32x4*)(ek + 512);
            er[r][3] = *(const f32x4*)(ek + 516);
        }
    }
    if (t < 64) { b_s[t] = 0.f; d_s[t] = 1.f / 64.f; }

    // W convert: block c owns 64x64 tile (bx=c&15, by=c>>4).
    {
        const int bx = c & 15, by = c >> 4;
        const int tx = t & 63, rg = t >> 6;
        for (int i = rg; i < 64; i += 8) {
            const size_t idx = (size_t)(by * 64 + i) * 1024 + bx * 64 + tx;
            const float v = W[idx];
            wtile[i][tx] = v;
            const BfPair p = split_bf16(v);
            Wb_hi[idx] = p.hi; Wb_lo[idx] = p.lo;
        }
        __syncthreads();
        for (int i = rg; i < 64; i += 8) {
            const size_t idx = (size_t)(bx * 64 + i) * 1024 + by * 64 + tx;
            const BfPair p = split_bf16(wtile[tx][i]);
            Wt_hi[idx] = p.hi; Wt_lo[idx] = p.lo;
        }
    }

    for (int it = 0; it < 3; ++it) {
        // ======== routing: b += E.u (it>0), softmax, s = sum d_k e_k ========
        if (it > 0) {
            f32x4 uf[4];
            {
                const size_t ub = (size_t)c * 1024 + lane * 8;
                #pragma unroll
                for (int q = 0; q < 4; ++q) {
                    const size_t o = ub + (q >> 1) * 512 + (q & 1) * 4;
                    f32x4 a = *(const f32x4*)(u0 + o);
                    f32x4 bb = *(const f32x4*)(u1 + o);
                    uf[q] = a + bb;
                }
            }
            #pragma unroll
            for (int r = 0; r < 8; ++r) {
                float sum = 0.f;
                #pragma unroll
                for (int q = 0; q < 4; ++q)
                    #pragma unroll
                    for (int j = 0; j < 4; ++j)
                        sum += er[r][q][j] * uf[q][j];
                #pragma unroll
                for (int off = 32; off; off >>= 1) sum += __shfl_xor(sum, off, 64);
                if (lane == 0) b_s[w * 8 + r] += sum;
            }
            __syncthreads();
            if (t < 64) {
                float bv = b_s[t], m = bv;
                #pragma unroll
                for (int off = 32; off; off >>= 1) m = fmaxf(m, __shfl_xor(m, off, 64));
                const float e = expf(bv - m);
                float sm = e;
                #pragma unroll
                for (int off = 32; off; off >>= 1) sm += __shfl_xor(sm, off, 64);
                d_s[t] = e / sm;
            }
        }
        __syncthreads();

        // per-wave partial s from registers
        #pragma unroll
        for (int q = 0; q < 4; ++q) {
            f32x4 p = {};
            #pragma unroll
            for (int r = 0; r < 8; ++r) {
                const float dk = d_s[w * 8 + r];
                #pragma unroll
                for (int j = 0; j < 4; ++j) p[j] += dk * er[r][q][j];
            }
            const int h = (q >> 1) * 512 + lane * 8 + (q & 1) * 4;
            *(f32x4*)&spart[w][h] = p;
        }
        __syncthreads();

        {   // cross-wave reduce; emit split-bf16 s
            const int h0 = t * 2;
            float a0 = 0.f, a1 = 0.f;
            #pragma unroll
            for (int wv = 0; wv < 8; ++wv) {
                f32x2 pv = *(const f32x2*)&spart[wv][h0];
                a0 += pv[0]; a1 += pv[1];
            }
            const BfPair p0 = split_bf16(a0), p1 = split_bf16(a1);
            bf16x2 hv, lv;
            hv[0] = p0.hi; hv[1] = p1.hi;
            lv[0] = p0.lo; lv[1] = p1.lo;
            *(bf16x2*)(s_hi + (size_t)c * 1024 + h0) = hv;
            *(bf16x2*)(s_lo + (size_t)c * 1024 + h0) = lv;
        }
        grid.sync();

        // ======== GEMM1: chat = s . Wb^T (split-K halves) ========
        gemm_phase(s_hi, s_lo, Wb_hi, Wb_lo, chat0, chat1, gw);
        grid.sync();

        // ======== squash ========
        {
            const int h0 = t * 2;
            const size_t o = (size_t)c * 1024 + h0;
            f32x2 pa = *(const f32x2*)(chat0 + o);
            f32x2 pb = *(const f32x2*)(chat1 + o);
            const float v0 = pa[0] + pb[0], v1 = pa[1] + pb[1];
            float ss = v0 * v0 + v1 * v1;
            #pragma unroll
            for (int off = 32; off; off >>= 1) ss += __shfl_xor(ss, off, 64);
            if (lane == 0) red_s[w] = ss;
            __syncthreads();
            float norm = 0.f;
            #pragma unroll
            for (int i = 0; i < 8; ++i) norm += red_s[i];
            const float scale = norm / ((1.f + norm) * sqrtf(norm) + 1e-30f);
            const float c0 = v0 * scale, c1 = v1 * scale;
            if (it < 2) {
                const BfPair p0 = split_bf16(c0), p1 = split_bf16(c1);
                bf16x2 hv, lv;
                hv[0] = p0.hi; hv[1] = p1.hi;
                lv[0] = p0.lo; lv[1] = p1.lo;
                *(bf16x2*)(c_hi + o) = hv;
                *(bf16x2*)(c_lo + o) = lv;
            } else {
                f32x2 ov; ov[0] = c0; ov[1] = c1;
                *(f32x2*)(outp + o) = ov;
            }
            __syncthreads();   // protect red_s reuse next iteration
        }

        if (it < 2) {
            grid.sync();
            // ======== GEMM2: u = cvec . Wt^T (split-K halves) ========
            gemm_phase(c_hi, c_lo, Wt_hi, Wt_lo, u0, u1, gw);
            grid.sync();
        }
    }
}

// ---------------- fallback: R3's proven monolithic fp32 kernel --------------
__global__ __launch_bounds__(512) void fallback_kernel(
    const float* __restrict__ enc, const float* __restrict__ W,
    float* __restrict__ outp)
{
    __shared__ float u_s[1024], s_s[1024], c_s[1024], chat_s[1024];
    __shared__ float b_s[64], d_s[64], red_s[8];
    const int t = threadIdx.x, lane = t & 63, w = t >> 6;
    const float* erow = enc + (size_t)blockIdx.x * 65536;

    if (t < 64) b_s[t] = 0.f;
    __syncthreads();

    for (int it = 0; it < 3; ++it) {
        if (it > 0) {
            f32x4 uf[4];
            #pragma unroll
            for (int q = 0; q < 2; ++q) {
                uf[2*q]   = *(const f32x4*)&u_s[q*512 + lane*8];
                uf[2*q+1] = *(const f32x4*)&u_s[q*512 + lane*8 + 4];
            }
            for (int r = 0; r < 8; ++r) {
                const int k = w * 8 + r;
                const float* ek = erow + (size_t)k * 1024;
                float sum = 0.f;
                #pragma unroll
                for (int q = 0; q < 2; ++q) {
                    f32x4 e0 = *(const f32x4*)(ek + q*512 + lane*8);
                    f32x4 e1 = *(const f32x4*)(ek + q*512 + lane*8 + 4);
                    #pragma unroll
                    for (int j = 0; j < 4; ++j) {
                        sum += e0[j] * uf[2*q][j];
                        sum += e1[j] * uf[2*q+1][j];
                    }
                }
                #pragma unroll
                for (int off = 32; off; off >>= 1) sum += __shfl_xor(sum, off, 64);
                if (lane == 0) b_s[k] += sum;
            }
            __syncthreads();
        }
        if (t < 64) {
            float bv = b_s[t], m = bv;
            #pragma unroll
            for (int off = 32; off; off >>= 1) m = fmaxf(m, __shfl_xor(m, off, 64));
            float e = expf(bv - m), sm = e;
            #pragma unroll
            for (int off = 32; off; off >>= 1) sm += __shfl_xor(sm, off, 64);
            d_s[t] = e / sm;
        }
        __syncthreads();
        {
            const int h0 = t * 2;
            float a0 = 0.f, a1 = 0.f;
            for (int k = 0; k < 64; ++k) {
                f32x2 ev = *(const f32x2*)(erow + (size_t)k * 1024 + h0);
                a0 += d_s[k] * ev[0]; a1 += d_s[k] * ev[1];
            }
            s_s[h0] = a0; s_s[h0+1] = a1;
        }
        __syncthreads();
        {
            f32x4 sf[4];
            #pragma unroll
            for (int q = 0; q < 2; ++q) {
                sf[2*q]   = *(const f32x4*)&s_s[q*512 + lane*8];
                sf[2*q+1] = *(const f32x4*)&s_s[q*512 + lane*8 + 4];
            }
            for (int r = 0; r < 128; ++r) {
                const int d = w * 128 + r;
                const float* wr = W + (size_t)d * 1024;
                float sum = 0.f;
                #pragma unroll
                for (int q = 0; q < 2; ++q) {
                    f32x4 w0 = *(const f32x4*)(wr + q*512 + lane*8);
                    f32x4 w1 = *(const f32x4*)(wr + q*512 + lane*8 + 4);
                    #pragma unroll
                    for (int j = 0; j < 4; ++j) {
                        sum += w0[j] * sf[2*q][j];
                        sum += w1[j] * sf[2*q+1][j];
                    }
                }
                #pragma unroll
                for (int off = 32; off; off >>= 1) sum += __shfl_xor(sum, off, 64);
                if (lane == 0) chat_s[d] = sum;
            }
        }
        __syncthreads();
        {
            const int h0 = t * 2;
            float v0 = chat_s[h0], v1 = chat_s[h0+1];
            float ss = v0*v0 + v1*v1;
            #pragma unroll
            for (int off = 32; off; off >>= 1) ss += __shfl_xor(ss, off, 64);
            if (lane == 0) red_s[w] = ss;
            __syncthreads();
            float norm = 0.f;
            #pragma unroll
            for (int i = 0; i < 8; ++i) norm += red_s[i];
            const float scale = norm / ((1.f + norm) * sqrtf(norm) + 1e-30f);
            c_s[h0] = v0 * scale; c_s[h0+1] = v1 * scale;
        }
        __syncthreads();
        if (it < 2) {
            const int h0 = t * 2;
            float uu0 = 0.f, uu1 = 0.f;
            for (int d = 0; d < 1024; ++d) {
                f32x2 wv = *(const f32x2*)(W + (size_t)d * 1024 + h0);
                uu0 += c_s[d] * wv[0]; uu1 += c_s[d] * wv[1];
            }
            u_s[h0] = uu0; u_s[h0+1] = uu1;
        } else {
            const int h0 = t * 2;
            f32x2 ov; ov[0] = c_s[h0]; ov[1] = c_s[h0+1];
            *(f32x2*)(outp + (size_t)blockIdx.x * 1024 + h0) = ov;
        }
        __syncthreads();
    }
}

extern "C" void kernel_launch(void* const* d_in, const int* in_sizes, int n_in,
                              void* d_out, int out_size, void* d_ws, size_t ws_size,
                              hipStream_t stream)
{
    const float* enc = (const float*)d_in[0];   // [256,64,1024] fp32
    const float* W   = (const float*)d_in[1];   // [1024,1024]   fp32
    float* outp = (float*)d_out;                // [256,1024]    fp32
    (void)in_sizes; (void)n_in; (void)out_size;

    // ws layout (14 MB)
    char* ws = (char*)d_ws;
    __bf16* s_hi  = (__bf16*)(ws + 0x000000);  // 512 KB
    __bf16* s_lo  = (__bf16*)(ws + 0x080000);  // 512 KB
    __bf16* c_hi  = (__bf16*)(ws + 0x100000);  // 512 KB
    __bf16* c_lo  = (__bf16*)(ws + 0x180000);  // 512 KB
    float*  chat0 = (float*) (ws + 0x200000);  //   1 MB
    float*  chat1 = (float*) (ws + 0x300000);  //   1 MB
    float*  u0    = (float*) (ws + 0x400000);  //   1 MB
    float*  u1    = (float*) (ws + 0x500000);  //   1 MB
    __bf16* Wb_hi = (__bf16*)(ws + 0x600000);  //   2 MB [d,h]
    __bf16* Wb_lo = (__bf16*)(ws + 0x800000);  //   2 MB [d,h]
    __bf16* Wt_hi = (__bf16*)(ws + 0xA00000);  //   2 MB [h,d]
    __bf16* Wt_lo = (__bf16*)(ws + 0xC00000);  //   2 MB [h,d]

    if (ws_size < 0xE00000) {
        fallback_kernel<<<256, 512, 0, stream>>>(enc, W, outp);
        return;
    }

    void* args[] = {
        (void*)&enc, (void*)&W, (void*)&outp,
        (void*)&s_hi, (void*)&s_lo, (void*)&c_hi, (void*)&c_lo,
        (void*)&chat0, (void*)&chat1, (void*)&u0, (void*)&u1,
        (void*)&Wb_hi, (void*)&Wb_lo, (void*)&Wt_hi, (void*)&Wt_lo
    };
    hipError_t err = hipLaunchCooperativeKernel(
        (void*)fused_kernel, dim3(256), dim3(512), args, 0, stream);
    if (err != hipSuccess) {
        // cooperative launch unavailable (e.g. capture incompat) -> safe path
        fallback_kernel<<<256, 512, 0, stream>>>(enc, W, outp);
    }
}

// Round 8
// 216.584 us; speedup vs baseline: 2.3327x; 2.3327x over previous
//
#include <hip/hip_runtime.h>

// InductionNetwork capsule routing, C=256, K=64, H=1024, 3 iterations.
// R7 post-mortem: cooperative grid.sync costs ~40us each on 8 XCDs ->
// 415us at 1% VALUBusy. Reverted to R6's 12-dispatch pipeline with the
// two occupancy fixes that R6 lacked:
//   - routing: 1024-thr blocks (16 waves/CU vs 8), enc in VGPRs (64/thread).
//   - GEMM: split-K x2 over 2048 waves as 512 blocks x 256 thr
//     (8 waves/CU vs R6's 1 wave/CU).
// Split-bf16 GEMM operands (verified R6/R7, absmax 4.88e-4):
//   D = Ah.Bh + Ah.Bl + Al.Bh with hi=bf16(x), lo=bf16(x-hi).
// Fallback: R3's proven monolithic kernel if ws too small.

using f32x4  = __attribute__((ext_vector_type(4))) float;
using f32x2  = __attribute__((ext_vector_type(2))) float;
using bf16x8 = __attribute__((ext_vector_type(8))) __bf16;
using bf16x2 = __attribute__((ext_vector_type(2))) __bf16;

struct BfPair { __bf16 hi, lo; };
__device__ inline BfPair split_bf16(float x) {
    BfPair p;
    p.hi = (__bf16)x;
    p.lo = (__bf16)(x - (float)p.hi);
    return p;
}

// ---------------- routing: b-update + softmax + weighted sum ----------------
// One block per capsule, 1024 threads = 16 waves. Wave w owns enc rows
// w*4..w*4+3; lane holds 16 floats/row (h = lane*8..+7, 512+lane*8..+7).
// MODE 0: d uniform (iter 0). MODE 1: b = E.u (store). MODE 2: b += E.u.
template <int MODE>
__global__ __launch_bounds__(1024) void routing_kernel(
    const float* __restrict__ enc, const float* __restrict__ u0,
    const float* __restrict__ u1, float* __restrict__ bglob,
    __bf16* __restrict__ s_hi, __bf16* __restrict__ s_lo)
{
    __shared__ float spart[16][1024];   // 64 KB: per-wave partial s
    __shared__ float b_s[64];
    __shared__ float d_s[64];

    const int t = threadIdx.x, lane = t & 63, w = t >> 6;   // 16 waves
    const int c = blockIdx.x;
    const float* E = enc + (size_t)c * 65536;

    f32x4 er[4][4];                     // 64 VGPRs of enc
    #pragma unroll
    for (int r = 0; r < 4; ++r) {
        const float* ek = E + (size_t)(w * 4 + r) * 1024 + lane * 8;
        er[r][0] = *(const f32x4*)(ek);
        er[r][1] = *(const f32x4*)(ek + 4);
        er[r][2] = *(const f32x4*)(ek + 512);
        er[r][3] = *(const f32x4*)(ek + 516);
    }

    if (MODE > 0) {
        const size_t ub = (size_t)c * 1024 + lane * 8;
        f32x4 uf[4];
        #pragma unroll
        for (int q = 0; q < 4; ++q) {
            const size_t o = ub + (q >> 1) * 512 + (q & 1) * 4;
            uf[q] = *(const f32x4*)(u0 + o) + *(const f32x4*)(u1 + o);
        }
        #pragma unroll
        for (int r = 0; r < 4; ++r) {
            float sum = 0.f;
            #pragma unroll
            for (int q = 0; q < 4; ++q)
                #pragma unroll
                for (int j = 0; j < 4; ++j)
                    sum += er[r][q][j] * uf[q][j];
            #pragma unroll
            for (int off = 32; off; off >>= 1) sum += __shfl_xor(sum, off, 64);
            if (lane == 0) {
                const int k = w * 4 + r;
                const float bv = (MODE == 2) ? (bglob[c * 64 + k] + sum) : sum;
                bglob[c * 64 + k] = bv;     // persist for next iteration
                b_s[k] = bv;
            }
        }
    }
    __syncthreads();

    if (MODE == 0) {
        if (t < 64) d_s[t] = 1.f / 64.f;
    } else if (t < 64) {
        float bv = b_s[t], m = bv;
        #pragma unroll
        for (int off = 32; off; off >>= 1) m = fmaxf(m, __shfl_xor(m, off, 64));
        const float e = expf(bv - m);
        float sm = e;
        #pragma unroll
        for (int off = 32; off; off >>= 1) sm += __shfl_xor(sm, off, 64);
        d_s[t] = e / sm;
    }
    __syncthreads();

    // per-wave partial s from registers (4 rows each)
    #pragma unroll
    for (int q = 0; q < 4; ++q) {
        f32x4 p = {};
        #pragma unroll
        for (int r = 0; r < 4; ++r) {
            const float dk = d_s[w * 4 + r];
            #pragma unroll
            for (int j = 0; j < 4; ++j) p[j] += dk * er[r][q][j];
        }
        const int h = (q >> 1) * 512 + lane * 8 + (q & 1) * 4;
        *(f32x4*)&spart[w][h] = p;
    }
    __syncthreads();

    // cross-wave reduce: 1 h-element per thread; emit split-bf16 s
    {
        float a = 0.f;
        #pragma unroll
        for (int wv = 0; wv < 16; ++wv) a += spart[wv][t];
        const BfPair p = split_bf16(a);
        s_hi[(size_t)c * 1024 + t] = p.hi;
        s_lo[(size_t)c * 1024 + t] = p.lo;
    }
}

// ---- split-bf16 NT GEMM, split-K x2: 2048 waves as 512 blocks x 4 waves.
// Wave gw: task=gw>>1 (mt=task>>6, nt=task&63), K-half kh=gw&1.
// Fragment layout verified R4/R6/R7: A[m=lane&15][k=(lane>>4)*8+j];
// C/D col=lane&15, row=(lane>>4)*4+reg.
__global__ __launch_bounds__(256) void gemm_split_kernel(
    const __bf16* __restrict__ Ah, const __bf16* __restrict__ Al,
    const __bf16* __restrict__ Bh, const __bf16* __restrict__ Bl,
    float* __restrict__ C0, float* __restrict__ C1)
{
    const int w = threadIdx.x >> 6;
    const int gw = blockIdx.x * 4 + w;
    const int task = gw >> 1;
    const int kh   = gw & 1;
    const int mt   = task >> 6;
    const int nt   = task & 63;
    const int lane = threadIdx.x & 63;
    const int kq   = (lane >> 4) * 8 + kh * 512;
    const size_t aoff = (size_t)(mt * 16 + (lane & 15)) * 1024 + kq;
    const size_t boff = (size_t)(nt * 16 + (lane & 15)) * 1024 + kq;

    f32x4 hh = {}, hl = {}, lh = {};
    #pragma unroll 4
    for (int k0 = 0; k0 < 512; k0 += 32) {
        bf16x8 ah = *(const bf16x8*)(Ah + aoff + k0);
        bf16x8 al = *(const bf16x8*)(Al + aoff + k0);
        bf16x8 bh = *(const bf16x8*)(Bh + boff + k0);
        bf16x8 bl = *(const bf16x8*)(Bl + boff + k0);
        hh = __builtin_amdgcn_mfma_f32_16x16x32_bf16(ah, bh, hh, 0, 0, 0);
        hl = __builtin_amdgcn_mfma_f32_16x16x32_bf16(ah, bl, hl, 0, 0, 0);
        lh = __builtin_amdgcn_mfma_f32_16x16x32_bf16(al, bh, lh, 0, 0, 0);
    }
    f32x4 acc = hh + hl + lh;
    float* Cc = kh ? C1 : C0;
    const int rr = (lane >> 4) * 4, colb = lane & 15;
    #pragma unroll
    for (int r = 0; r < 4; ++r)
        Cc[(size_t)(mt * 16 + rr + r) * 1024 + nt * 16 + colb] = acc[r];
}

// ---------------- squash: sums split-K partials, emits c + out --------------
__global__ __launch_bounds__(256) void squash_kernel(
    const float* __restrict__ chat0, const float* __restrict__ chat1,
    __bf16* __restrict__ c_hi, __bf16* __restrict__ c_lo,
    float* __restrict__ outp)
{
    __shared__ float wsum[4];
    const int c = blockIdx.x, t = threadIdx.x;
    const int lane = t & 63, w = t >> 6;
    const int h0 = t * 4;
    const size_t o = (size_t)c * 1024 + h0;
    f32x4 v = *(const f32x4*)(chat0 + o) + *(const f32x4*)(chat1 + o);
    float ss = v[0]*v[0] + v[1]*v[1] + v[2]*v[2] + v[3]*v[3];
    #pragma unroll
    for (int off = 32; off; off >>= 1) ss += __shfl_xor(ss, off, 64);
    if (lane == 0) wsum[w] = ss;
    __syncthreads();
    const float norm = wsum[0] + wsum[1] + wsum[2] + wsum[3];
    const float scale = norm / ((1.f + norm) * sqrtf(norm) + 1e-30f);
    f32x4 ov;
    __attribute__((ext_vector_type(4))) __bf16 hv, lv;
    #pragma unroll
    for (int j = 0; j < 4; ++j) {
        ov[j] = v[j] * scale;
        const BfPair p = split_bf16(ov[j]);
        hv[j] = p.hi; lv[j] = p.lo;
    }
    *(f32x4*)(outp + o) = ov;
    *(__attribute__((ext_vector_type(4))) __bf16*)(c_hi + o) = hv;
    *(__attribute__((ext_vector_type(4))) __bf16*)(c_lo + o) = lv;
}

// ---------------- W -> split bf16, direct + transposed ----------------------
__global__ __launch_bounds__(256) void convert_w_kernel(
    const float* __restrict__ W, __bf16* __restrict__ Wb_hi,
    __bf16* __restrict__ Wb_lo, __bf16* __restrict__ Wt_hi,
    __bf16* __restrict__ Wt_lo)
{
    __shared__ float tile[64][65];
    const int bx = blockIdx.x, by = blockIdx.y;
    const int tx = threadIdx.x & 63, ty = threadIdx.x >> 6;
    for (int i = ty; i < 64; i += 4) {
        const size_t idx = (size_t)(by * 64 + i) * 1024 + bx * 64 + tx;
        const float v = W[idx];
        tile[i][tx] = v;
        const BfPair p = split_bf16(v);
        Wb_hi[idx] = p.hi; Wb_lo[idx] = p.lo;
    }
    __syncthreads();
    for (int i = ty; i < 64; i += 4) {
        const size_t idx = (size_t)(bx * 64 + i) * 1024 + by * 64 + tx;
        const BfPair p = split_bf16(tile[tx][i]);
        Wt_hi[idx] = p.hi; Wt_lo[idx] = p.lo;
    }
}

// ---------------- fallback: R3's proven monolithic fp32 kernel --------------
__global__ __launch_bounds__(512) void fallback_kernel(
    const float* __restrict__ enc, const float* __restrict__ W,
    float* __restrict__ outp)
{
    __shared__ float u_s[1024], s_s[1024], c_s[1024], chat_s[1024];
    __shared__ float b_s[64], d_s[64], red_s[8];
    const int t = threadIdx.x, lane = t & 63, w = t >> 6;
    const float* erow = enc + (size_t)blockIdx.x * 65536;

    if (t < 64) b_s[t] = 0.f;
    __syncthreads();

    for (int it = 0; it < 3; ++it) {
        if (it > 0) {
            f32x4 uf[4];
            #pragma unroll
            for (int q = 0; q < 2; ++q) {
                uf[2*q]   = *(const f32x4*)&u_s[q*512 + lane*8];
                uf[2*q+1] = *(const f32x4*)&u_s[q*512 + lane*8 + 4];
            }
            for (int r = 0; r < 8; ++r) {
                const int k = w * 8 + r;
                const float* ek = erow + (size_t)k * 1024;
                float sum = 0.f;
                #pragma unroll
                for (int q = 0; q < 2; ++q) {
                    f32x4 e0 = *(const f32x4*)(ek + q*512 + lane*8);
                    f32x4 e1 = *(const f32x4*)(ek + q*512 + lane*8 + 4);
                    #pragma unroll
                    for (int j = 0; j < 4; ++j) {
                        sum += e0[j] * uf[2*q][j];
                        sum += e1[j] * uf[2*q+1][j];
                    }
                }
                #pragma unroll
                for (int off = 32; off; off >>= 1) sum += __shfl_xor(sum, off, 64);
                if (lane == 0) b_s[k] += sum;
            }
            __syncthreads();
        }
        if (t < 64) {
            float bv = b_s[t], m = bv;
            #pragma unroll
            for (int off = 32; off; off >>= 1) m = fmaxf(m, __shfl_xor(m, off, 64));
            float e = expf(bv - m), sm = e;
            #pragma unroll
            for (int off = 32; off; off >>= 1) sm += __shfl_xor(sm, off, 64);
            d_s[t] = e / sm;
        }
        __syncthreads();
        {
            const int h0 = t * 2;
            float a0 = 0.f, a1 = 0.f;
            for (int k = 0; k < 64; ++k) {
                f32x2 ev = *(const f32x2*)(erow + (size_t)k * 1024 + h0);
                a0 += d_s[k] * ev[0]; a1 += d_s[k] * ev[1];
            }
            s_s[h0] = a0; s_s[h0+1] = a1;
        }
        __syncthreads();
        {
            f32x4 sf[4];
            #pragma unroll
            for (int q = 0; q < 2; ++q) {
                sf[2*q]   = *(const f32x4*)&s_s[q*512 + lane*8];
                sf[2*q+1] = *(const f32x4*)&s_s[q*512 + lane*8 + 4];
            }
            for (int r = 0; r < 128; ++r) {
                const int d = w * 128 + r;
                const float* wr = W + (size_t)d * 1024;
                float sum = 0.f;
                #pragma unroll
                for (int q = 0; q < 2; ++q) {
                    f32x4 w0 = *(const f32x4*)(wr + q*512 + lane*8);
                    f32x4 w1 = *(const f32x4*)(wr + q*512 + lane*8 + 4);
                    #pragma unroll
                    for (int j = 0; j < 4; ++j) {
                        sum += w0[j] * sf[2*q][j];
                        sum += w1[j] * sf[2*q+1][j];
                    }
                }
                #pragma unroll
                for (int off = 32; off; off >>= 1) sum += __shfl_xor(sum, off, 64);
                if (lane == 0) chat_s[d] = sum;
            }
        }
        __syncthreads();
        {
            const int h0 = t * 2;
            float v0 = chat_s[h0], v1 = chat_s[h0+1];
            float ss = v0*v0 + v1*v1;
            #pragma unroll
            for (int off = 32; off; off >>= 1) ss += __shfl_xor(ss, off, 64);
            if (lane == 0) red_s[w] = ss;
            __syncthreads();
            float norm = 0.f;
            #pragma unroll
            for (int i = 0; i < 8; ++i) norm += red_s[i];
            const float scale = norm / ((1.f + norm) * sqrtf(norm) + 1e-30f);
            c_s[h0] = v0 * scale; c_s[h0+1] = v1 * scale;
        }
        __syncthreads();
        if (it < 2) {
            const int h0 = t * 2;
            float uu0 = 0.f, uu1 = 0.f;
            for (int d = 0; d < 1024; ++d) {
                f32x2 wv = *(const f32x2*)(W + (size_t)d * 1024 + h0);
                uu0 += c_s[d] * wv[0]; uu1 += c_s[d] * wv[1];
            }
            u_s[h0] = uu0; u_s[h0+1] = uu1;
        } else {
            const int h0 = t * 2;
            f32x2 ov; ov[0] = c_s[h0]; ov[1] = c_s[h0+1];
            *(f32x2*)(outp + (size_t)blockIdx.x * 1024 + h0) = ov;
        }
        __syncthreads();
    }
}

extern "C" void kernel_launch(void* const* d_in, const int* in_sizes, int n_in,
                              void* d_out, int out_size, void* d_ws, size_t ws_size,
                              hipStream_t stream)
{
    const float* enc = (const float*)d_in[0];   // [256,64,1024] fp32
    const float* W   = (const float*)d_in[1];   // [1024,1024]   fp32
    float* outp = (float*)d_out;                // [256,1024]    fp32
    (void)in_sizes; (void)n_in; (void)out_size;

    // ws layout (14.5 MB)
    char* ws = (char*)d_ws;
    float*  b     = (float*) (ws + 0x000000);  //  64 KB [256,64]
    __bf16* s_hi  = (__bf16*)(ws + 0x080000);  // 512 KB
    __bf16* s_lo  = (__bf16*)(ws + 0x100000);  // 512 KB
    __bf16* c_hi  = (__bf16*)(ws + 0x180000);  // 512 KB
    __bf16* c_lo  = (__bf16*)(ws + 0x200000);  // 512 KB
    float*  chat0 = (float*) (ws + 0x280000);  //   1 MB
    float*  chat1 = (float*) (ws + 0x380000);  //   1 MB
    float*  u0    = (float*) (ws + 0x480000);  //   1 MB
    float*  u1    = (float*) (ws + 0x580000);  //   1 MB
    __bf16* Wb_hi = (__bf16*)(ws + 0x680000);  //   2 MB [d,h]
    __bf16* Wb_lo = (__bf16*)(ws + 0x880000);  //   2 MB [d,h]
    __bf16* Wt_hi = (__bf16*)(ws + 0xA80000);  //   2 MB [h,d]
    __bf16* Wt_lo = (__bf16*)(ws + 0xC80000);  //   2 MB [h,d]

    if (ws_size < 0xE80000) {
        fallback_kernel<<<256, 512, 0, stream>>>(enc, W, outp);
        return;
    }

    convert_w_kernel<<<dim3(16, 16), 256, 0, stream>>>(W, Wb_hi, Wb_lo,
                                                       Wt_hi, Wt_lo);

    // iter 0
    routing_kernel<0><<<256, 1024, 0, stream>>>(enc, u0, u1, b, s_hi, s_lo);
    gemm_split_kernel<<<512, 256, 0, stream>>>(s_hi, s_lo, Wb_hi, Wb_lo,
                                               chat0, chat1);
    squash_kernel<<<256, 256, 0, stream>>>(chat0, chat1, c_hi, c_lo, outp);
    gemm_split_kernel<<<512, 256, 0, stream>>>(c_hi, c_lo, Wt_hi, Wt_lo,
                                               u0, u1);
    // iter 1
    routing_kernel<1><<<256, 1024, 0, stream>>>(enc, u0, u1, b, s_hi, s_lo);
    gemm_split_kernel<<<512, 256, 0, stream>>>(s_hi, s_lo, Wb_hi, Wb_lo,
                                               chat0, chat1);
    squash_kernel<<<256, 256, 0, stream>>>(chat0, chat1, c_hi, c_lo, outp);
    gemm_split_kernel<<<512, 256, 0, stream>>>(c_hi, c_lo, Wt_hi, Wt_lo,
                                               u0, u1);
    // iter 2
    routing_kernel<2><<<256, 1024, 0, stream>>>(enc, u0, u1, b, s_hi, s_lo);
    gemm_split_kernel<<<512, 256, 0, stream>>>(s_hi, s_lo, Wb_hi, Wb_lo,
                                               chat0, chat1);
    squash_kernel<<<256, 256, 0, stream>>>(chat0, chat1, c_hi, c_lo, outp);
}